// Round 1
// baseline (517.917 us; speedup 1.0000x reference)
//
#include <hip/hip_runtime.h>
#include <math.h>

// Problem constants (fixed by the reference)
#define B_SZ   4096      // batch
#define D      64        // embed dim
#define RPB    8192      // rows per branch = 2*B
#define NCHUNK 4         // column chunks per row-tile (occupancy)
#define CHUNK_COLS (RPB / NCHUNK)   // 2048
#define TILE   64
#define INV_T  5.0f      // 1/temperature

// ws layout (floats):
//   X : 2 branches * 8192 rows * 64  = 1,048,576 floats (4 MB)
//   P : 2 branches * 8192 rows * NCHUNK float2 (m,s) = 512 KB

// ---------------------------------------------------------------------------
// Gather + (user-branch) L2 normalize. One wave per output row.
// rows g in [0,16384): branch = g>>13 (0=user,1=item), r = g&8191,
// half = r>>12 (sub1/sub2), i = r&4095.
__global__ __launch_bounds__(256) void gather_kernel(
    const int* __restrict__ u_idx, const int* __restrict__ i_idx,
    const float* __restrict__ u1e, const float* __restrict__ i1e,
    const float* __restrict__ u2e, const float* __restrict__ i2e,
    float* __restrict__ X)
{
    const int tid  = threadIdx.x;
    const int wave = tid >> 6, lane = tid & 63;
    const int g      = blockIdx.x * 4 + wave;   // 0..16383
    const int branch = g >> 13;
    const int r      = g & (RPB - 1);
    const int half   = r >> 12;
    const int i      = r & (B_SZ - 1);
    const int idx    = (branch == 0) ? u_idx[i] : i_idx[i];
    const float* src = (branch == 0) ? (half == 0 ? u1e : u2e)
                                     : (half == 0 ? i1e : i2e);
    float v = src[(size_t)idx * D + lane];
    if (branch == 0) {
        float s = v * v;
        #pragma unroll
        for (int o = 32; o > 0; o >>= 1) s += __shfl_xor(s, o, 64);
        v = v / sqrtf(s);   // reference: u / ||u||
    }
    X[(size_t)g * D + lane] = v;
}

// ---------------------------------------------------------------------------
// Diagonal (positive-pair) correction: out -= (1/B) * (v1_i . v2_i) / T
// One wave per i per branch.
__global__ __launch_bounds__(256) void t_kernel(
    const float* __restrict__ X, float* __restrict__ out)
{
    const int tid  = threadIdx.x;
    const int wave = tid >> 6, lane = tid & 63;
    const int g      = blockIdx.x * 4 + wave;   // 0..8191
    const int branch = g >> 12;
    const int i      = g & (B_SZ - 1);
    const float* x1 = X + ((size_t)branch * RPB + i) * D;
    const float* x2 = x1 + (size_t)B_SZ * D;
    float p = x1[lane] * x2[lane];
    #pragma unroll
    for (int o = 32; o > 0; o >>= 1) p += __shfl_xor(p, o, 64);
    if (lane == 0) atomicAdd(out, -p * (INV_T / (float)B_SZ));
}

// ---------------------------------------------------------------------------
// Fused Gram + online row-logsumexp.
// grid = (RPB/TILE, NCHUNK, 2). block = 256 (16x16 threads, 4x4 reg tile).
// Writes per-(row,chunk) partial (m, s) to P.
__global__ __launch_bounds__(256) void gram_lse_kernel(
    const float* __restrict__ X, float2* __restrict__ P)
{
    // transposed tiles, stride 68: 16B-aligned float4 reads;
    // A-read = 16-lane broadcast (free), B-read = 2-way (free).
    __shared__ float At[64][68];
    __shared__ float Bt[64][68];

    const int tid     = threadIdx.x;
    const int branch  = blockIdx.z;
    const int rowTile = blockIdx.x;
    const int chunk   = blockIdx.y;
    const float* Xb = X + (size_t)branch * RPB * D;
    const int r0 = rowTile * TILE;

    // Load A tile (64 rows), transposed into At[k][r]
    #pragma unroll
    for (int p = 0; p < 4; ++p) {
        int e   = p * 256 + tid;       // 0..1023 float4 slots
        int row = e >> 4;              // 0..63
        int c4  = e & 15;              // float4 index within row
        const float4 v = *(const float4*)(Xb + (size_t)(r0 + row) * D + c4 * 4);
        At[c4 * 4 + 0][row] = v.x;
        At[c4 * 4 + 1][row] = v.y;
        At[c4 * 4 + 2][row] = v.z;
        At[c4 * 4 + 3][row] = v.w;
    }

    const int ty = tid >> 4, tx = tid & 15;
    float m_run[4], s_run[4];
    #pragma unroll
    for (int i = 0; i < 4; ++i) { m_run[i] = -INFINITY; s_run[i] = 0.f; }

    const int c0 = chunk * CHUNK_COLS;
    for (int t = 0; t < CHUNK_COLS / TILE; ++t) {
        const int cb = c0 + t * TILE;
        __syncthreads();
        #pragma unroll
        for (int p = 0; p < 4; ++p) {
            int e   = p * 256 + tid;
            int row = e >> 4;
            int c4  = e & 15;
            const float4 v = *(const float4*)(Xb + (size_t)(cb + row) * D + c4 * 4);
            Bt[c4 * 4 + 0][row] = v.x;
            Bt[c4 * 4 + 1][row] = v.y;
            Bt[c4 * 4 + 2][row] = v.z;
            Bt[c4 * 4 + 3][row] = v.w;
        }
        __syncthreads();

        float acc[4][4];
        #pragma unroll
        for (int i = 0; i < 4; ++i)
            #pragma unroll
            for (int j = 0; j < 4; ++j) acc[i][j] = 0.f;

        #pragma unroll 16
        for (int k = 0; k < 64; ++k) {
            const float4 a = *(const float4*)&At[k][ty * 4];
            const float4 b = *(const float4*)&Bt[k][tx * 4];
            acc[0][0] = fmaf(a.x, b.x, acc[0][0]);
            acc[0][1] = fmaf(a.x, b.y, acc[0][1]);
            acc[0][2] = fmaf(a.x, b.z, acc[0][2]);
            acc[0][3] = fmaf(a.x, b.w, acc[0][3]);
            acc[1][0] = fmaf(a.y, b.x, acc[1][0]);
            acc[1][1] = fmaf(a.y, b.y, acc[1][1]);
            acc[1][2] = fmaf(a.y, b.z, acc[1][2]);
            acc[1][3] = fmaf(a.y, b.w, acc[1][3]);
            acc[2][0] = fmaf(a.z, b.x, acc[2][0]);
            acc[2][1] = fmaf(a.z, b.y, acc[2][1]);
            acc[2][2] = fmaf(a.z, b.z, acc[2][2]);
            acc[2][3] = fmaf(a.z, b.w, acc[2][3]);
            acc[3][0] = fmaf(a.w, b.x, acc[3][0]);
            acc[3][1] = fmaf(a.w, b.y, acc[3][1]);
            acc[3][2] = fmaf(a.w, b.z, acc[3][2]);
            acc[3][3] = fmaf(a.w, b.w, acc[3][3]);
        }

        // scale by 1/T, mask Gram diagonal, online logsumexp per row
        const int gr0 = r0 + ty * 4;
        const int gc0 = cb + tx * 4;
        #pragma unroll
        for (int i = 0; i < 4; ++i) {
            float x[4];
            #pragma unroll
            for (int j = 0; j < 4; ++j) {
                x[j] = acc[i][j] * INV_T;
                if (gr0 + i == gc0 + j) x[j] = -INFINITY;
            }
            float mt = fmaxf(fmaxf(x[0], x[1]), fmaxf(x[2], x[3]));
            #pragma unroll
            for (int o = 1; o < 16; o <<= 1) mt = fmaxf(mt, __shfl_xor(mt, o, 64));
            const float newm = fmaxf(m_run[i], mt);   // finite after 1st tile
            float st = __expf(x[0] - newm) + __expf(x[1] - newm)
                     + __expf(x[2] - newm) + __expf(x[3] - newm);
            #pragma unroll
            for (int o = 1; o < 16; o <<= 1) st += __shfl_xor(st, o, 64);
            s_run[i] = s_run[i] * __expf(m_run[i] - newm) + st;
            m_run[i] = newm;
        }
    }

    if (tx == 0) {
        #pragma unroll
        for (int i = 0; i < 4; ++i) {
            const int row = r0 + ty * 4 + i;
            P[((size_t)branch * RPB + row) * NCHUNK + chunk] =
                make_float2(m_run[i], s_run[i]);
        }
    }
}

// ---------------------------------------------------------------------------
// Merge chunk partials -> lse per row -> out += lse / (2B)
__global__ __launch_bounds__(256) void merge_kernel(
    const float2* __restrict__ P, float* __restrict__ out)
{
    const int g = blockIdx.x * 256 + threadIdx.x;  // 0..16383
    float2 p[NCHUNK];
    #pragma unroll
    for (int c = 0; c < NCHUNK; ++c) p[c] = P[(size_t)g * NCHUNK + c];
    float M = p[0].x;
    #pragma unroll
    for (int c = 1; c < NCHUNK; ++c) M = fmaxf(M, p[c].x);
    float S = 0.f;
    #pragma unroll
    for (int c = 0; c < NCHUNK; ++c) S += p[c].y * __expf(p[c].x - M);
    float v = (M + logf(S)) * (1.0f / (float)RPB);  // /(2B)
    #pragma unroll
    for (int o = 32; o > 0; o >>= 1) v += __shfl_xor(v, o, 64);
    if ((threadIdx.x & 63) == 0) atomicAdd(out, v);
}

// ---------------------------------------------------------------------------
extern "C" void kernel_launch(void* const* d_in, const int* in_sizes, int n_in,
                              void* d_out, int out_size, void* d_ws, size_t ws_size,
                              hipStream_t stream) {
    const int*   u_idx = (const int*)d_in[0];
    const int*   i_idx = (const int*)d_in[1];
    const float* u1e   = (const float*)d_in[2];
    const float* i1e   = (const float*)d_in[3];
    const float* u2e   = (const float*)d_in[4];
    const float* i2e   = (const float*)d_in[5];
    float* out = (float*)d_out;

    float*  X = (float*)d_ws;                       // 2*8192*64 floats
    float2* P = (float2*)(X + 2 * RPB * D);         // 2*8192*NCHUNK float2

    hipMemsetAsync(out, 0, sizeof(float), stream);

    gather_kernel<<<dim3(4096), dim3(256), 0, stream>>>(u_idx, i_idx, u1e, i1e, u2e, i2e, X);
    t_kernel<<<dim3(2048), dim3(256), 0, stream>>>(X, out);
    dim3 grid(RPB / TILE, NCHUNK, 2);               // 128 x 4 x 2 = 1024 blocks
    gram_lse_kernel<<<grid, dim3(256), 0, stream>>>(X, P);
    merge_kernel<<<dim3(64), dim3(256), 0, stream>>>(P, out);
}

// Round 2
// 221.022 us; speedup vs baseline: 2.3433x; 2.3433x over previous
//
#include <hip/hip_runtime.h>
#include <hip/hip_bf16.h>
#include <math.h>

// Problem constants (fixed by the reference)
#define B_SZ   4096                 // batch
#define D      64                   // embed dim
#define RPB    8192                 // rows per branch = 2*B
#define NCHUNK 8                    // column chunks (blockIdx.y)
#define TPC    8                    // 128-col tiles per chunk (8*8*128 = 8192)
#define SCALE  7.2134752044448169f  // (1/T) * log2(e) = 5 * 1.4426950408889634
#define LN2    0.69314718055994531f

typedef __attribute__((ext_vector_type(8))) short  bf16x8;
typedef __attribute__((ext_vector_type(4))) float  f32x4;

// ws layout:
//   Xbf  : 2*8192*64 bf16   = 2 MB   (row-major, [branch][row][k])
//   dots : 8192 float       = 32 KB  (v1_i . v2_i per (branch,i))
//   P    : 16384*8 float2   = 1 MB   (per-row per-chunk (m,s) partials, base-2)

// ---------------------------------------------------------------------------
// Gather + (user) L2-normalize + bf16 cast + positive-pair dot.
// One wave per (branch, i) pair: handles rows i and i+B of that branch.
__global__ __launch_bounds__(256) void gather_kernel(
    const int* __restrict__ u_idx, const int* __restrict__ i_idx,
    const float* __restrict__ u1e, const float* __restrict__ i1e,
    const float* __restrict__ u2e, const float* __restrict__ i2e,
    __hip_bfloat16* __restrict__ Xbf, float* __restrict__ dots)
{
    const int tid  = threadIdx.x;
    const int wave = tid >> 6, lane = tid & 63;
    const int g      = blockIdx.x * 4 + wave;   // 0..8191
    const int branch = g >> 12;
    const int i      = g & (B_SZ - 1);
    const int idx    = (branch == 0) ? u_idx[i] : i_idx[i];
    const float* s1  = (branch == 0) ? u1e : i1e;
    const float* s2  = (branch == 0) ? u2e : i2e;

    float v1 = s1[(size_t)idx * D + lane];
    float v2 = s2[(size_t)idx * D + lane];
    if (branch == 0) {
        float a = v1 * v1, b = v2 * v2;
        #pragma unroll
        for (int o = 32; o > 0; o >>= 1) {
            a += __shfl_xor(a, o, 64);
            b += __shfl_xor(b, o, 64);
        }
        v1 *= rsqrtf(a);
        v2 *= rsqrtf(b);
    }
    float p = v1 * v2;
    #pragma unroll
    for (int o = 32; o > 0; o >>= 1) p += __shfl_xor(p, o, 64);
    if (lane == 0) dots[g] = p;

    const size_t row1 = (size_t)branch * RPB + i;         // v1 row
    Xbf[row1 * D + lane]               = __float2bfloat16(v1);
    Xbf[(row1 + B_SZ) * D + lane]      = __float2bfloat16(v2);
}

// ---------------------------------------------------------------------------
// MFMA Gram + fused online row-logsumexp (base-2 domain).
// grid = (64 row-tiles, 8 chunks, 2 branches); block = 256 (4 waves, 2x2).
// Each block: C tile 128 rows x (8 x 128) cols, K=64 staged once for A.
__global__ __launch_bounds__(256, 4) void gram_lse_kernel(
    const __hip_bfloat16* __restrict__ Xbf, float2* __restrict__ P)
{
    __shared__ __align__(16) __hip_bfloat16 As[128][72];  // +8 pad: b128 r/w BW-minimal
    __shared__ __align__(16) __hip_bfloat16 Bs[128][72];
    __shared__ float2 sm[2][128];                         // running (m,s) per row per wn

    const int tid   = threadIdx.x;
    const int bx    = blockIdx.x;          // row tile
    const int chunk = blockIdx.y;
    const int bz    = blockIdx.z;          // branch
    const int r0    = bx * 128;
    const __hip_bfloat16* Xb = Xbf + (size_t)bz * RPB * D;

    // Stage A panel (128 rows x 64 k, bf16) once.
    #pragma unroll
    for (int p = 0; p < 4; ++p) {
        int e = p * 256 + tid;             // 1024 x 16B chunks
        int row = e >> 3, c8 = e & 7;
        *(uint4*)&As[row][c8 * 8] =
            *(const uint4*)(Xb + (size_t)(r0 + row) * D + c8 * 8);
    }
    sm[tid >> 7][tid & 127] = make_float2(-INFINITY, 0.f);

    const int wave = tid >> 6, lane = tid & 63;
    const int wm = wave >> 1, wn = wave & 1;
    const int quad = lane >> 4, tx = lane & 15;

    for (int t = 0; t < TPC; ++t) {
        const int ct = chunk * TPC + t;    // global 128-col tile index
        const int c0 = ct * 128;
        __syncthreads();                   // prior reads of Bs done (also covers As/sm init)
        #pragma unroll
        for (int p = 0; p < 4; ++p) {
            int e = p * 256 + tid;
            int row = e >> 3, c8 = e & 7;
            *(uint4*)&Bs[row][c8 * 8] =
                *(const uint4*)(Xb + (size_t)(c0 + row) * D + c8 * 8);
        }
        __syncthreads();

        f32x4 acc[4][4];
        #pragma unroll
        for (int i = 0; i < 4; ++i)
            #pragma unroll
            for (int j = 0; j < 4; ++j) acc[i][j] = (f32x4){0.f, 0.f, 0.f, 0.f};

        #pragma unroll
        for (int ks = 0; ks < 2; ++ks) {
            bf16x8 bfr[4];
            #pragma unroll
            for (int nt = 0; nt < 4; ++nt)
                bfr[nt] = *(const bf16x8*)&Bs[wn * 64 + nt * 16 + tx][ks * 32 + quad * 8];
            #pragma unroll
            for (int mt = 0; mt < 4; ++mt) {
                bf16x8 afr = *(const bf16x8*)&As[wm * 64 + mt * 16 + tx][ks * 32 + quad * 8];
                #pragma unroll
                for (int nt = 0; nt < 4; ++nt)
                    acc[mt][nt] = __builtin_amdgcn_mfma_f32_16x16x32_bf16(
                        afr, bfr[nt], acc[mt][nt], 0, 0, 0);
            }
        }

        // Epilogue: scale to base-2 logits, mask Gram diagonal (only when
        // this col tile overlaps the row tile), online LSE into sm.
        const bool diag = (ct == bx);
        #pragma unroll
        for (int mt = 0; mt < 4; ++mt) {
            #pragma unroll
            for (int rr = 0; rr < 4; ++rr) {
                float y[4];
                #pragma unroll
                for (int nt = 0; nt < 4; ++nt) y[nt] = acc[mt][nt][rr] * SCALE;
                if (diag) {
                    const int grow = r0 + wm * 64 + mt * 16 + quad * 4 + rr;
                    #pragma unroll
                    for (int nt = 0; nt < 4; ++nt) {
                        const int gcol = c0 + wn * 64 + nt * 16 + tx;
                        if (grow == gcol) y[nt] = -INFINITY;
                    }
                }
                float mx = fmaxf(fmaxf(y[0], y[1]), fmaxf(y[2], y[3]));
                #pragma unroll
                for (int o = 1; o < 16; o <<= 1) mx = fmaxf(mx, __shfl_xor(mx, o, 64));
                float st = exp2f(y[0] - mx) + exp2f(y[1] - mx)
                         + exp2f(y[2] - mx) + exp2f(y[3] - mx);
                #pragma unroll
                for (int o = 1; o < 16; o <<= 1) st += __shfl_xor(st, o, 64);
                if (tx == 0) {
                    const int row = wm * 64 + mt * 16 + quad * 4 + rr;  // block-local
                    float2 old = sm[wn][row];
                    float M = fmaxf(old.x, mx);
                    float S = old.y * exp2f(old.x - M) + st * exp2f(mx - M);
                    sm[wn][row] = make_float2(M, S);
                }
            }
        }
    }

    __syncthreads();
    if (tid < 128) {
        float2 p0 = sm[0][tid], p1 = sm[1][tid];
        float M = fmaxf(p0.x, p1.x);
        float S = p0.y * exp2f(p0.x - M) + p1.y * exp2f(p1.x - M);
        const size_t grow = (size_t)bz * RPB + r0 + tid;
        P[grow * NCHUNK + chunk] = make_float2(M, S);
    }
}

// ---------------------------------------------------------------------------
// Merge chunk partials -> per-row lse -> block-reduced atomic; also folds in
// the positive-pair (diagonal) correction from dots[].
__global__ __launch_bounds__(256) void merge_kernel(
    const float2* __restrict__ P, const float* __restrict__ dots,
    float* __restrict__ out)
{
    __shared__ float red[4];
    const int tid  = threadIdx.x;
    const int wave = tid >> 6, lane = tid & 63;
    const int gw   = blockIdx.x * 4 + wave;        // 0..2047
    const int row  = gw * 8 + (lane >> 3);         // 0..16383
    const int c    = lane & 7;

    float2 p = P[(size_t)row * NCHUNK + c];
    float M = p.x;
    #pragma unroll
    for (int o = 1; o < 8; o <<= 1) M = fmaxf(M, __shfl_xor(M, o, 64));
    float S = p.y * exp2f(p.x - M);
    #pragma unroll
    for (int o = 1; o < 8; o <<= 1) S += __shfl_xor(S, o, 64);

    float v = 0.f;
    if ((lane & 7) == 0)
        v = LN2 * (M + log2f(S)) * (1.0f / (float)RPB);   // lse_row / (2B)
    if (tid < 16)                                          // diag correction
        v -= dots[blockIdx.x * 16 + tid] * (5.0f / (float)B_SZ);

    #pragma unroll
    for (int o = 32; o > 0; o >>= 1) v += __shfl_xor(v, o, 64);
    if (lane == 0) red[wave] = v;
    __syncthreads();
    if (tid == 0)
        atomicAdd(out, red[0] + red[1] + red[2] + red[3]);
}

// ---------------------------------------------------------------------------
extern "C" void kernel_launch(void* const* d_in, const int* in_sizes, int n_in,
                              void* d_out, int out_size, void* d_ws, size_t ws_size,
                              hipStream_t stream) {
    const int*   u_idx = (const int*)d_in[0];
    const int*   i_idx = (const int*)d_in[1];
    const float* u1e   = (const float*)d_in[2];
    const float* i1e   = (const float*)d_in[3];
    const float* u2e   = (const float*)d_in[4];
    const float* i2e   = (const float*)d_in[5];
    float* out = (float*)d_out;

    __hip_bfloat16* Xbf = (__hip_bfloat16*)d_ws;                  // 2 MB
    float*  dots = (float*)((char*)d_ws + 2 * RPB * D * 2);       // 32 KB
    float2* P    = (float2*)((char*)dots + RPB * sizeof(float));  // 1 MB

    hipMemsetAsync(out, 0, sizeof(float), stream);

    gather_kernel<<<dim3(2048), dim3(256), 0, stream>>>(
        u_idx, i_idx, u1e, i1e, u2e, i2e, Xbf, dots);
    gram_lse_kernel<<<dim3(64, NCHUNK, 2), dim3(256), 0, stream>>>(Xbf, P);
    merge_kernel<<<dim3(512), dim3(256), 0, stream>>>(P, dots, out);
}

// Round 4
// 176.075 us; speedup vs baseline: 2.9415x; 1.2553x over previous
//
#include <hip/hip_runtime.h>
#include <hip/hip_bf16.h>
#include <math.h>

// Problem constants (fixed by the reference)
#define B_SZ   4096
#define D      64
#define RPB    8192                 // rows per branch = 2*B
#define NCHUNK 8                    // column chunks (blockIdx.y)
#define TPC    8                    // 128-col tiles per chunk
#define NPART  16                   // partials per row = NCHUNK * 2 (wn halves)
#define LN2    0.69314718055994531f
#define PRESCALE 2.6857914f         // sqrt(5 * log2(e)); X pre-scaled so Gram = base-2 logits

typedef __attribute__((ext_vector_type(8))) short  bf16x8;
typedef __attribute__((ext_vector_type(4))) float  f32x4;

__device__ __forceinline__ float fexp2(float x) { return __builtin_amdgcn_exp2f(x); }

// ws layout:
//   Xbf  : 2*8192*64 bf16  = 2 MB   (pre-scaled by PRESCALE)
//   dots : 8192 float      = 32 KB  (v1_i . v2_i, unscaled fp32)
//   P    : 16384*16 float2 = 2 MB   (per-row per-(chunk,wn) (m,s), base-2; user m=0)

// ---------------------------------------------------------------------------
__global__ __launch_bounds__(256) void gather_kernel(
    const int* __restrict__ u_idx, const int* __restrict__ i_idx,
    const float* __restrict__ u1e, const float* __restrict__ i1e,
    const float* __restrict__ u2e, const float* __restrict__ i2e,
    __hip_bfloat16* __restrict__ Xbf, float* __restrict__ dots)
{
    const int tid  = threadIdx.x;
    const int wave = tid >> 6, lane = tid & 63;
    const int g      = blockIdx.x * 4 + wave;   // 0..8191
    const int branch = g >> 12;
    const int i      = g & (B_SZ - 1);
    const int idx    = (branch == 0) ? u_idx[i] : i_idx[i];
    const float* s1  = (branch == 0) ? u1e : i1e;
    const float* s2  = (branch == 0) ? u2e : i2e;

    float v1 = s1[(size_t)idx * D + lane];
    float v2 = s2[(size_t)idx * D + lane];
    if (branch == 0) {
        float a = v1 * v1, b = v2 * v2;
        #pragma unroll
        for (int o = 32; o > 0; o >>= 1) {
            a += __shfl_xor(a, o, 64);
            b += __shfl_xor(b, o, 64);
        }
        v1 *= rsqrtf(a);
        v2 *= rsqrtf(b);
    }
    float p = v1 * v2;
    #pragma unroll
    for (int o = 32; o > 0; o >>= 1) p += __shfl_xor(p, o, 64);
    if (lane == 0) dots[g] = p;

    const size_t row1 = (size_t)branch * RPB + i;
    Xbf[row1 * D + lane]          = __float2bfloat16(v1 * PRESCALE);
    Xbf[(row1 + B_SZ) * D + lane] = __float2bfloat16(v2 * PRESCALE);
}

// ---------------------------------------------------------------------------
// MFMA Gram + per-lane online logsumexp (base-2). grid=(64 row-tiles, 8 chunks).
// Block: 4 waves, each owns a 64x64 C subtile (4x4 MFMA 16x16x32, K=64).
// Each (row, chunk, wn) partial gets its OWN P slot (wn halves merged in
// merge_kernel -- R3 bug was both wn waves clobbering one slot).
// IS_USER=1: logits bounded (|y|<=7.3) -> no max tracking, plain exp2-sum.
template<int IS_USER>
__global__ __launch_bounds__(256, 3) void gram_lse_kernel(
    const __hip_bfloat16* __restrict__ Xb, float2* __restrict__ P)
{
    __shared__ __align__(16) __hip_bfloat16 Bs[128][72];  // +8 pad -> ~2-way (free)

    const int tid   = threadIdx.x;
    const int bx    = blockIdx.x;
    const int chunk = blockIdx.y;
    const int r0    = bx * 128;

    const int wave = tid >> 6, lane = tid & 63;
    const int wm = wave >> 1, wn = wave & 1;
    const int quad = lane >> 4, tx = lane & 15;

    // Stage A panel through Bs, hoist A fragments to registers (K=64 fits).
    #pragma unroll
    for (int p = 0; p < 4; ++p) {
        int e = p * 256 + tid;
        int row = e >> 3, c8 = e & 7;
        *(uint4*)&Bs[row][c8 * 8] =
            *(const uint4*)(Xb + (size_t)(r0 + row) * D + c8 * 8);
    }
    __syncthreads();
    bf16x8 afr[4][2];
    #pragma unroll
    for (int mt = 0; mt < 4; ++mt)
        #pragma unroll
        for (int ks = 0; ks < 2; ++ks)
            afr[mt][ks] = *(const bf16x8*)&Bs[wm * 64 + mt * 16 + tx][ks * 32 + quad * 8];

    float m_run[16], s_run[16];
    #pragma unroll
    for (int r = 0; r < 16; ++r) { m_run[r] = -INFINITY; s_run[r] = 0.f; }

    const int lrq  = wm * 64 + quad * 4;   // + mt*16 + rr = block-local row
    const int lcol = wn * 64 + tx;         // + nt*16      = block-local col

    for (int t = 0; t < TPC; ++t) {
        const int ct = chunk * TPC + t;
        const int c0 = ct * 128;
        __syncthreads();                   // afr reads (t=0) / prior B-frag reads done
        #pragma unroll
        for (int p = 0; p < 4; ++p) {
            int e = p * 256 + tid;
            int row = e >> 3, c8 = e & 7;
            *(uint4*)&Bs[row][c8 * 8] =
                *(const uint4*)(Xb + (size_t)(c0 + row) * D + c8 * 8);
        }
        __syncthreads();

        f32x4 acc[4][4];
        const f32x4 z = {0.f, 0.f, 0.f, 0.f};
        #pragma unroll
        for (int nt = 0; nt < 4; ++nt) {
            const bf16x8 b0 = *(const bf16x8*)&Bs[wn * 64 + nt * 16 + tx][quad * 8];
            #pragma unroll
            for (int mt = 0; mt < 4; ++mt)
                acc[mt][nt] = __builtin_amdgcn_mfma_f32_16x16x32_bf16(afr[mt][0], b0, z, 0, 0, 0);
        }
        #pragma unroll
        for (int nt = 0; nt < 4; ++nt) {
            const bf16x8 b1 = *(const bf16x8*)&Bs[wn * 64 + nt * 16 + tx][32 + quad * 8];
            #pragma unroll
            for (int mt = 0; mt < 4; ++mt)
                acc[mt][nt] = __builtin_amdgcn_mfma_f32_16x16x32_bf16(afr[mt][1], b1, acc[mt][nt], 0, 0, 0);
        }

        const bool diag = (ct == bx);
        #pragma unroll
        for (int mt = 0; mt < 4; ++mt) {
            #pragma unroll
            for (int rr = 0; rr < 4; ++rr) {
                float y0 = acc[mt][0][rr], y1 = acc[mt][1][rr],
                      y2 = acc[mt][2][rr], y3 = acc[mt][3][rr];
                if (diag) {                  // acc already = base-2 logits (pre-scaled X)
                    const int dr = lrq + mt * 16 + rr - lcol;
                    if (dr == 0)  y0 = -INFINITY;
                    if (dr == 16) y1 = -INFINITY;
                    if (dr == 32) y2 = -INFINITY;
                    if (dr == 48) y3 = -INFINITY;
                }
                const int r = mt * 4 + rr;
                if (IS_USER) {
                    s_run[r] += fexp2(y0) + fexp2(y1) + fexp2(y2) + fexp2(y3);
                } else {
                    float mx   = fmaxf(fmaxf(y0, y1), fmaxf(y2, y3));
                    float newm = fmaxf(m_run[r], mx);
                    s_run[r] = s_run[r] * fexp2(m_run[r] - newm)
                             + fexp2(y0 - newm) + fexp2(y1 - newm)
                             + fexp2(y2 - newm) + fexp2(y3 - newm);
                    m_run[r] = newm;
                }
            }
        }
    }

    // Once per chunk: merge across the 16 tx lanes of THIS wave, write the
    // (row, chunk, wn) partial to its own slot.
    #pragma unroll
    for (int r = 0; r < 16; ++r) {
        float m = IS_USER ? 0.f : m_run[r];
        float s = s_run[r];
        #pragma unroll
        for (int o = 1; o < 16; o <<= 1) {
            if (IS_USER) {
                s += __shfl_xor(s, o, 64);
            } else {
                float om = __shfl_xor(m, o, 64);
                float os = __shfl_xor(s, o, 64);
                float M  = fmaxf(m, om);
                s = s * fexp2(m - M) + os * fexp2(om - M);
                m = M;
            }
        }
        if (tx == 0) {
            const int grow = r0 + wm * 64 + (r >> 2) * 16 + quad * 4 + (r & 3);
            P[(size_t)grow * NPART + chunk * 2 + wn] = make_float2(m, s);
        }
    }
}

// ---------------------------------------------------------------------------
// Merge the 16 per-row partials -> lse -> reduce; fold in the positive-pair
// correction from dots[]. grid = 1024 x 256 (each block: 16 rows, 8 dots).
__global__ __launch_bounds__(256) void merge_kernel(
    const float2* __restrict__ P, const float* __restrict__ dots,
    float* __restrict__ out)
{
    __shared__ float red[4];
    const int tid  = threadIdx.x;
    const int wave = tid >> 6, lane = tid & 63;
    const int gw   = blockIdx.x * 4 + wave;        // 0..4095
    const int row  = gw * 4 + (lane >> 4);         // 0..16383
    const int c    = lane & 15;

    float2 p = P[(size_t)row * NPART + c];
    float m = p.x, s = p.y;
    #pragma unroll
    for (int o = 1; o < 16; o <<= 1) {             // online merge across 16 lanes
        float om = __shfl_xor(m, o, 64);
        float os = __shfl_xor(s, o, 64);
        float M  = fmaxf(m, om);
        s = s * fexp2(m - M) + os * fexp2(om - M);
        m = M;
    }

    float v = 0.f;
    if ((lane & 15) == 0)
        v = LN2 * (m + log2f(s)) * (1.0f / (float)RPB);   // lse_row / (2B)
    if (tid < 8)                                           // positive-pair correction
        v -= dots[blockIdx.x * 8 + tid] * (5.0f / (float)B_SZ);

    #pragma unroll
    for (int o = 32; o > 0; o >>= 1) v += __shfl_xor(v, o, 64);
    if (lane == 0) red[wave] = v;
    __syncthreads();
    if (tid == 0)
        atomicAdd(out, red[0] + red[1] + red[2] + red[3]);
}

// ---------------------------------------------------------------------------
extern "C" void kernel_launch(void* const* d_in, const int* in_sizes, int n_in,
                              void* d_out, int out_size, void* d_ws, size_t ws_size,
                              hipStream_t stream) {
    const int*   u_idx = (const int*)d_in[0];
    const int*   i_idx = (const int*)d_in[1];
    const float* u1e   = (const float*)d_in[2];
    const float* i1e   = (const float*)d_in[3];
    const float* u2e   = (const float*)d_in[4];
    const float* i2e   = (const float*)d_in[5];
    float* out = (float*)d_out;

    __hip_bfloat16* Xbf = (__hip_bfloat16*)d_ws;                  // 2 MB
    float*  dots = (float*)((char*)d_ws + 2 * RPB * D * 2);       // 32 KB
    float2* P    = (float2*)((char*)dots + RPB * sizeof(float));  // 2 MB

    hipMemsetAsync(out, 0, sizeof(float), stream);

    gather_kernel<<<dim3(2048), dim3(256), 0, stream>>>(
        u_idx, i_idx, u1e, i1e, u2e, i2e, Xbf, dots);
    // user branch (bounded logits: no max tracking)
    gram_lse_kernel<1><<<dim3(64, NCHUNK), dim3(256), 0, stream>>>(Xbf, P);
    // item branch (online max)
    gram_lse_kernel<0><<<dim3(64, NCHUNK), dim3(256), 0, stream>>>(
        Xbf + (size_t)RPB * D, P + (size_t)RPB * NPART);
    merge_kernel<<<dim3(1024), dim3(256), 0, stream>>>(P, dots, out);
}